// Round 5
// baseline (273.078 us; speedup 1.0000x reference)
//
#include <hip/hip_runtime.h>

// Problem constants: B=16, T=64, N=128, D=512, H=512, O=256, A=18
#define DD 512
#define HH 512
#define OO 256
#define AA 18
#define NBLK 256
#define NTHR 512

// Phase-overlaid LDS. P1: 34816+20480+9216 = 64512 B (just under 64 KiB).
struct P1m { float As[4][32][68]; float Bs[4][32][40]; float Gs[64][36]; };
struct P2m { float As[4][32][36]; float Bs[4][32][40]; float Gs[32][36]; };
struct P3m { float sW[OO * AA]; float sT[4][OO + 4]; };
union SMem { P1m p1; P2m p2; P3m p3; };
static_assert(sizeof(SMem) <= 64 * 1024, "LDS overflow");

// Device-scope grid barrier (all NBLK blocks co-resident by resource math:
// 8 waves/block, 64.5KB LDS -> 2 blocks/CU capacity, grid == 1 per CU).
__device__ __forceinline__ void gridbar(unsigned* cnt, unsigned* gen) {
  __threadfence();   // release this thread's stores to device scope
  __syncthreads();
  if (threadIdx.x == 0) {
    unsigned g = __hip_atomic_load(gen, __ATOMIC_RELAXED, __HIP_MEMORY_SCOPE_AGENT);
    unsigned a = __hip_atomic_fetch_add(cnt, 1u, __ATOMIC_ACQ_REL, __HIP_MEMORY_SCOPE_AGENT);
    if (a == NBLK - 1) {
      __hip_atomic_store(cnt, 0u, __ATOMIC_RELAXED, __HIP_MEMORY_SCOPE_AGENT);
      __hip_atomic_fetch_add(gen, 1u, __ATOMIC_ACQ_REL, __HIP_MEMORY_SCOPE_AGENT);
    } else {
      while (__hip_atomic_load(gen, __ATOMIC_ACQUIRE, __HIP_MEMORY_SCOPE_AGENT) == g)
        __builtin_amdgcn_s_sleep(16);
    }
  }
  __syncthreads();
  __threadfence();   // acquire: no stale cache reads of other XCDs' data
}

__global__ __launch_bounds__(NTHR) void fused(
    const float* __restrict__ obs, const float* __restrict__ W1,
    const float* __restrict__ b1, const float* __restrict__ W2,
    const float* __restrict__ b2, const float* __restrict__ Wl,
    const float* __restrict__ bl, float* __restrict__ out,
    float* __restrict__ U, float* __restrict__ Tg,
    unsigned* __restrict__ cnt, unsigned* __restrict__ gen) {
  __shared__ SMem sm;
  const int tid = threadIdx.x;
  const int blk = blockIdx.x;

  // ============ Phase 1: U = pathGCN1(obs @ W1) ============
  // Tile 64x32 (rows == one batch), grid-mapped (16 col-tiles x 16 row-tiles).
  // 4 K-groups x 128 threads; each group: K-slice of 128 = 4 tiles of BK=32.
  {
    const int col0 = (blk & 15) * 32;
    const int row0 = (blk >> 4) * 64;
    const int gid = tid >> 7, gt = tid & 127;
    const int kbase = gid * 128;
    const int ar = gt >> 1, ah = (gt & 1) * 16;   // A: row, col-half
    const int br = gt >> 2, b4 = (gt & 3) * 4;    // B: row, f4-slot
    const int ty = gt >> 3, tx = gt & 7;          // micro 4x4: rows ty*4, cols tx*4
    float4 pa[4], pb[2];
    float acc[4][4] = {};

    auto loadg = [&](int kb) {
      const float* Ap = obs + (size_t)(row0 + ar) * DD + kb + ah;
#pragma unroll
      for (int q = 0; q < 4; ++q) pa[q] = *(const float4*)(Ap + q * 4);
      const float* Bp = W1 + (size_t)(kb + br) * HH + col0 + b4;
      pb[0] = *(const float4*)(Bp);
      pb[1] = *(const float4*)(Bp + 16);
    };
    auto stolds = [&]() {
#pragma unroll
      for (int q = 0; q < 4; ++q) {
        const int c = ah + q * 4;
        sm.p1.As[gid][c + 0][ar] = pa[q].x;
        sm.p1.As[gid][c + 1][ar] = pa[q].y;
        sm.p1.As[gid][c + 2][ar] = pa[q].z;
        sm.p1.As[gid][c + 3][ar] = pa[q].w;
      }
      *(float4*)&sm.p1.Bs[gid][br][b4] = pb[0];
      *(float4*)&sm.p1.Bs[gid][br][b4 + 16] = pb[1];
    };
    auto comp = [&]() {
#pragma unroll
      for (int kk = 0; kk < 32; ++kk) {
        const float4 av = *(const float4*)&sm.p1.As[gid][kk][ty * 4];
        const float4 bv = *(const float4*)&sm.p1.Bs[gid][kk][tx * 4];
        acc[0][0] = fmaf(av.x, bv.x, acc[0][0]);
        acc[0][1] = fmaf(av.x, bv.y, acc[0][1]);
        acc[0][2] = fmaf(av.x, bv.z, acc[0][2]);
        acc[0][3] = fmaf(av.x, bv.w, acc[0][3]);
        acc[1][0] = fmaf(av.y, bv.x, acc[1][0]);
        acc[1][1] = fmaf(av.y, bv.y, acc[1][1]);
        acc[1][2] = fmaf(av.y, bv.z, acc[1][2]);
        acc[1][3] = fmaf(av.y, bv.w, acc[1][3]);
        acc[2][0] = fmaf(av.z, bv.x, acc[2][0]);
        acc[2][1] = fmaf(av.z, bv.y, acc[2][1]);
        acc[2][2] = fmaf(av.z, bv.z, acc[2][2]);
        acc[2][3] = fmaf(av.z, bv.w, acc[2][3]);
        acc[3][0] = fmaf(av.w, bv.x, acc[3][0]);
        acc[3][1] = fmaf(av.w, bv.y, acc[3][1]);
        acc[3][2] = fmaf(av.w, bv.z, acc[3][2]);
        acc[3][3] = fmaf(av.w, bv.w, acc[3][3]);
      }
    };

    loadg(kbase);
    stolds();
    __syncthreads();
    for (int t = 0; t < 4; ++t) {
      if (t < 3) loadg(kbase + (t + 1) * 32);
      comp();
      __syncthreads();
      if (t < 3) {
        stolds();
        __syncthreads();
      }
    }

    // Reduce the 4 K-group partials into Gs.
    for (int i = tid; i < 64 * 36; i += NTHR) ((float*)sm.p1.Gs)[i] = 0.f;
    __syncthreads();
#pragma unroll
    for (int i = 0; i < 4; ++i)
#pragma unroll
      for (int j = 0; j < 4; ++j)
        atomicAdd(&sm.p1.Gs[ty * 4 + i][tx * 4 + j], acc[i][j]);
    __syncthreads();

    // Path-GCN layer-1 combine: t == local row (tile == one batch).
    const int rr = tid >> 3;
    const int cg = (tid & 7) * 4;
    const int t = rr;
    const float is6 = 0.4082482904638630f;  // 1/sqrt(6)
    float c0, c1, c2, d1, d2, al, be;
    if (t <= 1) {
      c0 = 0.f; c1 = 0.f; c2 = 1.f; d1 = 0.f; d2 = 0.f; al = 1.f; be = 0.f;
    } else if (t == 2) {
      c0 = 0.f; c1 = 0.5f; c2 = 0.5f; d1 = 0.5f; d2 = 0.5f; al = 0.5f; be = 0.5f;
    } else {
      c0 = (t == 3) ? is6 : (1.f / 3.f);
      c1 = 1.f / 3.f; c2 = is6;
      d1 = is6; d2 = 0.5f;
      al = is6; be = 0.5f;
    }
    const int rm1 = (rr >= 1) ? rr - 1 : 0;
    const int rm2 = (rr >= 2) ? rr - 2 : 0;
    const float4 gcv = *(const float4*)&sm.p1.Gs[rr][cg];
    const float4 gbv = *(const float4*)&sm.p1.Gs[rm1][cg];
    const float4 gav = *(const float4*)&sm.p1.Gs[rm2][cg];
    const float4 bbv = *(const float4*)&b1[col0 + cg];
    float4 u;
#define ONE(fld)                                                               \
    {                                                                          \
      float h1a = fmaxf(c0 * gav.fld + c1 * gbv.fld + c2 * gcv.fld + bbv.fld, 0.f); \
      float h1b = fmaxf(d1 * gbv.fld + d2 * gcv.fld + bbv.fld, 0.f);           \
      u.fld = al * h1a + be * h1b;                                             \
    }
    ONE(x) ONE(y) ONE(z) ONE(w)
#undef ONE
    *(float4*)&U[(size_t)(row0 + rr) * HH + col0 + cg] = u;
  }

  gridbar(cnt, gen);

  // ============ Phase 2: Tg = relu(U @ W2 + b2) ============
  // Tile 32x32, grid-mapped (8 col-tiles x 32 row-tiles) = 256 blocks.
  {
    const int col0 = (blk & 7) * 32;
    const int row0 = (blk >> 3) * 32;
    const int gid = tid >> 7, gt = tid & 127;
    const int kbase = gid * 128;
    const int ar = gt >> 2, a4 = (gt & 3) * 4;   // both tiles 32x32
    const int ty = gt >> 4, tx = gt & 15;        // micro 4x2
    float4 pa[2], pb[2];
    float acc[4][2] = {};

    auto loadg = [&](int kb) {
      const float* Ap = U + (size_t)(row0 + ar) * HH + kb + a4;
      pa[0] = *(const float4*)(Ap);
      pa[1] = *(const float4*)(Ap + 16);
      const float* Bp = W2 + (size_t)(kb + ar) * OO + col0 + a4;
      pb[0] = *(const float4*)(Bp);
      pb[1] = *(const float4*)(Bp + 16);
    };
    auto stolds = [&]() {
#pragma unroll
      for (int q = 0; q < 2; ++q) {
        const int c = a4 + q * 16;
        sm.p2.As[gid][c + 0][ar] = pa[q].x;
        sm.p2.As[gid][c + 1][ar] = pa[q].y;
        sm.p2.As[gid][c + 2][ar] = pa[q].z;
        sm.p2.As[gid][c + 3][ar] = pa[q].w;
      }
      *(float4*)&sm.p2.Bs[gid][ar][a4] = pb[0];
      *(float4*)&sm.p2.Bs[gid][ar][a4 + 16] = pb[1];
    };
    auto comp = [&]() {
#pragma unroll
      for (int kk = 0; kk < 32; ++kk) {
        const float4 av = *(const float4*)&sm.p2.As[gid][kk][ty * 4];
        const float2 bv = *(const float2*)&sm.p2.Bs[gid][kk][tx * 2];
        acc[0][0] = fmaf(av.x, bv.x, acc[0][0]);
        acc[0][1] = fmaf(av.x, bv.y, acc[0][1]);
        acc[1][0] = fmaf(av.y, bv.x, acc[1][0]);
        acc[1][1] = fmaf(av.y, bv.y, acc[1][1]);
        acc[2][0] = fmaf(av.z, bv.x, acc[2][0]);
        acc[2][1] = fmaf(av.z, bv.y, acc[2][1]);
        acc[3][0] = fmaf(av.w, bv.x, acc[3][0]);
        acc[3][1] = fmaf(av.w, bv.y, acc[3][1]);
      }
    };

    loadg(kbase);
    stolds();
    __syncthreads();
    for (int t = 0; t < 4; ++t) {
      if (t < 3) loadg(kbase + (t + 1) * 32);
      comp();
      __syncthreads();
      if (t < 3) {
        stolds();
        __syncthreads();
      }
    }

    for (int i = tid; i < 32 * 36; i += NTHR) ((float*)sm.p2.Gs)[i] = 0.f;
    __syncthreads();
#pragma unroll
    for (int i = 0; i < 4; ++i)
#pragma unroll
      for (int j = 0; j < 2; ++j)
        atomicAdd(&sm.p2.Gs[ty * 4 + i][tx * 2 + j], acc[i][j]);
    __syncthreads();

    for (int i = tid; i < 32 * 32; i += NTHR) {
      const int r = i >> 5, c = i & 31;
      Tg[(size_t)(row0 + r) * OO + col0 + c] =
          fmaxf(sm.p2.Gs[r][c] + b2[col0 + c], 0.f);
    }
  }

  gridbar(cnt, gen);

  // ============ Phase 3: out = Tg @ Wl + bl (4 rows/block) ============
  {
    const int r0 = blk * 4;
    for (int i = tid; i < OO * AA; i += NTHR) sm.p3.sW[i] = Wl[i];
    for (int i = tid; i < 4 * OO; i += NTHR) {
      const int m = i >> 8, k = i & 255;
      sm.p3.sT[m][k] = Tg[(size_t)(r0 + m) * OO + k];
    }
    __syncthreads();
    if (tid < 4 * AA) {
      const int m = tid / AA, o = tid - m * AA;
      float s = bl[o];
#pragma unroll 8
      for (int k = 0; k < OO; ++k)
        s = fmaf(sm.p3.sT[m][k], sm.p3.sW[k * AA + o], s);
      out[(size_t)(r0 + m) * AA + o] = s;
    }
  }
}

extern "C" void kernel_launch(void* const* d_in, const int* in_sizes, int n_in,
                              void* d_out, int out_size, void* d_ws, size_t ws_size,
                              hipStream_t stream) {
  const float* obs = (const float*)d_in[0];   // [1024, 512]
  const float* W1 = (const float*)d_in[4];    // [512, 512]
  const float* b1 = (const float*)d_in[5];    // [512]
  const float* W2 = (const float*)d_in[6];    // [512, 256]
  const float* b2 = (const float*)d_in[7];    // [256]
  const float* Wl = (const float*)d_in[8];    // [256, 18]
  const float* bl = (const float*)d_in[9];    // [18]
  float* out = (float*)d_out;                 // [1024, 18]

  float* U = (float*)d_ws;                          // 1024x512 = 2 MiB
  float* Tg = U + (size_t)1024 * HH;                // 1024x256 = 1 MiB
  unsigned* bar = (unsigned*)((char*)d_ws + 3u * 1024 * 1024);

  hipMemsetAsync(bar, 0, 2 * sizeof(unsigned), stream);
  fused<<<NBLK, NTHR, 0, stream>>>(obs, W1, b1, W2, b2, Wl, bl, out, U, Tg,
                                   bar, bar + 1);
}

// Round 6
// 40.475 us; speedup vs baseline: 6.7468x; 6.7468x over previous
//
#include <hip/hip_runtime.h>

// Problem constants: B=16, T=64, N=128, D=512, H=512, O=256, A=18
#define TT 64
#define DD 512
#define HH 512
#define OO 256
#define AA 18
#define ROWS 1024

// ---------------------------------------------------------------------------
// Split-K tiled f32 GEMM (round-2-proven codegen): P[z] = A @ B K-slice
// partials. BM=64, BK=32, 256 threads, micro-tile 4x(BN/16), register
// prefetch, single LDS buffer, 2 barriers/tile. Grid: (N/BN, M/64, KS).
// ---------------------------------------------------------------------------
template <int BN, int KS>
__global__ __launch_bounds__(256) void gemm_sk(
    const float* __restrict__ A, const float* __restrict__ Bm,
    float* __restrict__ P, int M, int N, int K) {
  constexpr int BM = 64, BK = 32, TM = 4, TN = BN / 16;
  constexpr int AF4 = BM * BK / (256 * 4);   // 2
  constexpr int BF4 = BK * BN / (256 * 4);   // 2 (BN=64)
  constexpr int BN4 = BN / 4;

  __shared__ float As[BK][BM];   // stored transposed: As[k][m]
  __shared__ float Bs[BK][BN];

  const int tid = threadIdx.x;
  const int tx = tid & 15, ty = tid >> 4;
  const int col0 = blockIdx.x * BN;
  const int row0 = blockIdx.y * BM;
  const int Kc = K / KS;
  const int k0 = blockIdx.z * Kc;

  float4 pa[AF4], pb[BF4];

#define LOADG(kb)                                                              \
  {                                                                            \
    _Pragma("unroll") for (int q = 0; q < AF4; ++q) {                          \
      int f = tid + q * 256;                                                   \
      int ar = f >> 3, ac = f & 7;                                             \
      pa[q] = *reinterpret_cast<const float4*>(                                \
          &A[(size_t)(row0 + ar) * K + (kb) + ac * 4]);                        \
    }                                                                          \
    _Pragma("unroll") for (int q = 0; q < BF4; ++q) {                          \
      int f = tid + q * 256;                                                   \
      int br = f / BN4, bc = f % BN4;                                          \
      pb[q] = *reinterpret_cast<const float4*>(                                \
          &Bm[(size_t)((kb) + br) * N + col0 + bc * 4]);                       \
    }                                                                          \
  }

#define STOLDS()                                                               \
  {                                                                            \
    _Pragma("unroll") for (int q = 0; q < AF4; ++q) {                          \
      int f = tid + q * 256;                                                   \
      int ar = f >> 3, ac = f & 7;                                             \
      As[ac * 4 + 0][ar] = pa[q].x;                                            \
      As[ac * 4 + 1][ar] = pa[q].y;                                            \
      As[ac * 4 + 2][ar] = pa[q].z;                                            \
      As[ac * 4 + 3][ar] = pa[q].w;                                            \
    }                                                                          \
    _Pragma("unroll") for (int q = 0; q < BF4; ++q) {                          \
      int f = tid + q * 256;                                                   \
      int br = f / BN4, bc = f % BN4;                                          \
      *reinterpret_cast<float4*>(&Bs[br][bc * 4]) = pb[q];                     \
    }                                                                          \
  }

#define COMPUTE()                                                              \
  {                                                                            \
    _Pragma("unroll") for (int kk = 0; kk < BK; ++kk) {                        \
      float a[TM], b[TN];                                                      \
      _Pragma("unroll") for (int i = 0; i < TM; ++i)                           \
          a[i] = As[kk][ty * TM + i];                                          \
      _Pragma("unroll") for (int j = 0; j < TN; ++j)                           \
          b[j] = Bs[kk][tx * TN + j];                                          \
      _Pragma("unroll") for (int i = 0; i < TM; ++i)                           \
          _Pragma("unroll") for (int j = 0; j < TN; ++j)                       \
              acc[i][j] = fmaf(a[i], b[j], acc[i][j]);                         \
    }                                                                          \
  }

  float acc[TM][TN] = {};

  LOADG(k0);
  STOLDS();
  __syncthreads();

  for (int kb = k0 + BK; kb < k0 + Kc; kb += BK) {
    LOADG(kb);       // next-tile global loads hide under compute
    COMPUTE();
    __syncthreads();
    STOLDS();
    __syncthreads();
  }
  COMPUTE();

  float* Pz = P + (size_t)blockIdx.z * M * N;
#pragma unroll
  for (int i = 0; i < TM; ++i) {
    int r = row0 + ty * TM + i;
#pragma unroll
    for (int j = 0; j < TN; ++j)
      Pz[(size_t)r * N + col0 + tx * TN + j] = acc[i][j];
  }
#undef LOADG
#undef STOLDS
#undef COMPUTE
}

// ---------------------------------------------------------------------------
// combine4: reduce 4 split-K partials of G, then path-GCN layer-1 combine.
// One block per row r; 128 threads, one float4 per thread.
// ---------------------------------------------------------------------------
__global__ __launch_bounds__(128) void combine4(
    const float* __restrict__ Gp, const float* __restrict__ b1,
    float* __restrict__ U) {
  const int r = blockIdx.x;
  const int t = r % TT;

  const float is6 = 0.4082482904638630f;  // 1/sqrt(6)
  float c0, c1, c2, d1, d2, al, be;
  if (t <= 1) {
    c0 = 0.f; c1 = 0.f; c2 = 1.f; d1 = 0.f; d2 = 0.f; al = 1.f; be = 0.f;
  } else if (t == 2) {
    c0 = 0.f; c1 = 0.5f; c2 = 0.5f; d1 = 0.5f; d2 = 0.5f; al = 0.5f; be = 0.5f;
  } else {
    c0 = (t == 3) ? is6 : (1.f / 3.f);
    c1 = 1.f / 3.f; c2 = is6;
    d1 = is6; d2 = 0.5f;
    al = is6; be = 0.5f;
  }

  constexpr size_t SZ = (size_t)ROWS * HH;
  const int k4 = threadIdx.x * 4;

  auto grow = [&](int rr) -> float4 {
    const size_t o = (size_t)rr * HH + k4;
    float4 s = *reinterpret_cast<const float4*>(&Gp[o]);
#pragma unroll
    for (int z = 1; z < 4; ++z) {
      const float4 q = *reinterpret_cast<const float4*>(&Gp[z * SZ + o]);
      s.x += q.x; s.y += q.y; s.z += q.z; s.w += q.w;
    }
    return s;
  };

  const float4 gc = grow(r);
  const float4 gb = (t >= 1) ? grow(r - 1) : gc;
  const float4 ga = (t >= 2) ? grow(r - 2) : gc;
  const float4 bb = *reinterpret_cast<const float4*>(&b1[k4]);

  float4 u;
#define ONE(fld)                                                               \
  {                                                                            \
    float h1a = fmaxf(c0 * ga.fld + c1 * gb.fld + c2 * gc.fld + bb.fld, 0.f);  \
    float h1b = fmaxf(d1 * gb.fld + d2 * gc.fld + bb.fld, 0.f);                \
    u.fld = al * h1a + be * h1b;                                               \
  }
  ONE(x) ONE(y) ONE(z) ONE(w)
#undef ONE
  *reinterpret_cast<float4*>(&U[(size_t)r * HH + k4]) = u;
}

// ---------------------------------------------------------------------------
// head8: reduce 8 split-K partials of U@W2, +b2, relu -> tgt; tgt @ Wl + bl.
// 8 rows per block, grid 128.
// ---------------------------------------------------------------------------
__global__ __launch_bounds__(256) void head8(
    const float* __restrict__ Tp, const float* __restrict__ b2,
    const float* __restrict__ Wl, const float* __restrict__ bl,
    float* __restrict__ out) {
  __shared__ float sW[OO * AA];      // 18 KiB
  __shared__ float sT[8][OO + 8];

  constexpr size_t TSZ = (size_t)ROWS * OO;
  const int tid = threadIdx.x;
  for (int i = tid; i < OO * AA; i += 256) sW[i] = Wl[i];
  const int r0 = blockIdx.x * 8;
  for (int i = tid; i < 8 * OO; i += 256) {
    const int m = i >> 8, k = i & 255;
    const size_t g = (size_t)(r0 + m) * OO + k;
    float s = b2[k];
#pragma unroll
    for (int z = 0; z < 8; ++z) s += Tp[z * TSZ + g];
    sT[m][k] = fmaxf(s, 0.f);
  }
  __syncthreads();

  if (tid < 8 * AA) {
    const int m = tid / AA;
    const int o = tid - m * AA;
    float s = bl[o];
#pragma unroll 8
    for (int k = 0; k < OO; ++k) s = fmaf(sT[m][k], sW[k * AA + o], s);
    out[(size_t)(r0 + m) * AA + o] = s;
  }
}

extern "C" void kernel_launch(void* const* d_in, const int* in_sizes, int n_in,
                              void* d_out, int out_size, void* d_ws, size_t ws_size,
                              hipStream_t stream) {
  const float* obs = (const float*)d_in[0];   // [1024, 512]
  const float* W1 = (const float*)d_in[4];    // [512, 512]
  const float* b1 = (const float*)d_in[5];    // [512]
  const float* W2 = (const float*)d_in[6];    // [512, 256]
  const float* b2 = (const float*)d_in[7];    // [256]
  const float* Wl = (const float*)d_in[8];    // [256, 18]
  const float* bl = (const float*)d_in[9];    // [18]
  float* out = (float*)d_out;                 // [1024, 18]

  float* Gp = (float*)d_ws;                        // 4 x 1024x512 = 8 MiB
  float* U  = Gp + 4 * (size_t)ROWS * HH;          // 1024x512     = 2 MiB
  float* Tp = U + (size_t)ROWS * HH;               // 8 x 1024x256 = 8 MiB

  // 1) Gp = obs @ W1 partials, split-K x4. Grid (8,16,4) = 512 blocks.
  gemm_sk<64, 4><<<dim3(HH / 64, ROWS / 64, 4), 256, 0, stream>>>(
      obs, W1, Gp, ROWS, HH, DD);

  // 2) U: reduce 4 partials + path-GCN layer-1. 1024 blocks.
  combine4<<<ROWS, 128, 0, stream>>>(Gp, b1, U);

  // 3) Tp = U @ W2 partials, split-K x8. Grid (4,16,8) = 512 blocks.
  gemm_sk<64, 8><<<dim3(OO / 64, ROWS / 64, 8), 256, 0, stream>>>(
      U, W2, Tp, ROWS, OO, HH);

  // 4) head: reduce 8 partials + b2 + relu + @Wl + bl. 128 blocks.
  head8<<<ROWS / 8, 256, 0, stream>>>(Tp, b2, Wl, bl, out);
}